// Round 11
// baseline (182.557 us; speedup 1.0000x reference)
//
#include <hip/hip_runtime.h>
#include <hip/hip_bf16.h>
#include <hip/hip_fp16.h>
#include <math.h>

typedef short v8s __attribute__((ext_vector_type(8)));
typedef short v4s __attribute__((ext_vector_type(4)));
typedef float v4f __attribute__((ext_vector_type(4)));
typedef unsigned short ushort_t;

__device__ __forceinline__ unsigned short f2bf(float f) {
    unsigned int u = __float_as_uint(f);
    u = (u + 0x7FFFu + ((u >> 16) & 1u)) >> 16;   // RNE
    return (unsigned short)u;
}
__device__ __forceinline__ unsigned short f2h(float f) {
    __half h = __float2half(f);
    return *reinterpret_cast<unsigned short*>(&h);
}
__device__ __forceinline__ float h2f(unsigned short u) {
    __half h = *reinterpret_cast<__half*>(&u);
    return __half2float(h);
}

__device__ __forceinline__ void load_lds16(const void* g, void* l) {
    __builtin_amdgcn_global_load_lds((const __attribute__((address_space(1))) void*)g,
                                     (__attribute__((address_space(3))) void*)l,
                                     16, 0, 0);
}

#define FENCE() asm volatile("" ::: "memory")
#define BAR() do { FENCE(); __builtin_amdgcn_s_barrier(); FENCE(); } while (0)
#define LGKM0() asm volatile("s_waitcnt lgkmcnt(0)" ::: "memory")
#define VMC(n) asm volatile("s_waitcnt vmcnt(" #n ")" ::: "memory")

// ---------------------------------------------------------------------------
__global__ __launch_bounds__(256) void cvt_kernel(const float4* __restrict__ in,
                                                  ushort_t* __restrict__ out, int n4) {
    int i = blockIdx.x * 256 + threadIdx.x;
    int stride = gridDim.x * 256;
    for (; i < n4; i += stride) {
        float4 v = in[i];
        v4s p;
        p[0] = (short)f2bf(v.x); p[1] = (short)f2bf(v.y);
        p[2] = (short)f2bf(v.z); p[3] = (short)f2bf(v.w);
        *(v4s*)(out + (size_t)i * 4) = p;
    }
}

// ---------------------------------------------------------------------------
__global__ void transpose_w(const float* __restrict__ W0, const float* __restrict__ W1,
                            const float* __restrict__ W2, ushort_t* __restrict__ WtAll) {
    const float* W = (blockIdx.z == 0) ? W0 : (blockIdx.z == 1 ? W1 : W2);
    ushort_t* out = WtAll + (size_t)blockIdx.z * 1024 * 1024;
    __shared__ float tile[32][33];
    int n0 = blockIdx.x * 32, k0 = blockIdx.y * 32;
    int tx = threadIdx.x, ty = threadIdx.y;       // block (32, 8)
    #pragma unroll
    for (int i = 0; i < 32; i += 8)
        tile[ty + i][tx] = W[(size_t)(k0 + ty + i) * 1024 + n0 + tx];
    __syncthreads();
    #pragma unroll
    for (int i = 0; i < 32; i += 8)
        out[(size_t)(n0 + ty + i) * 1024 + k0 + tx] = f2bf(tile[tx][ty + i]);
}

// ---------------------------------------------------------------------------
// 256x256-tile 8-phase GEMM (m201-geometry port). 512 thr, 8 waves (2Mx4N),
// per-wave 128x64 out (acc 8x4, 64 MFMA/K-tile). BK=64, LDS = 2buf x
// 2K-half x 256x32 x {A,B} = 128 KB. Iter u consumes K-tiles t0=2u (buf0),
// t1=2u+1 (buf1) in 8 phases; phase = (K-half, M-half): pre-barrier ds_reads
// (8 or 4 x b128), one half-tile stage (2 gload_lds/thread), BAR,
// lgkmcnt(0), setprio(1), 16 MFMA, setprio(0), BAR.
// Stage schedule (ledger-verified): ph1 A-kh1(t1), ph2 B-kh1(t1),
// ph3 A-kh0(t0+2), ph4 B-kh0(t0+2) +vmcnt(4), ph5 A-kh1(t0+2),
// ph6 B-kh1(t0+2), ph7 A-kh0(t1+2), ph8 B-kh0(t1+2) +vmcnt(4).
// vmcnt(4)@ph4 completes the 4 half-tiles ph5-8 read; vmcnt(4)@ph8
// completes next iter's t0; 2 half-tiles always in flight.
// Swizzle: 16B chunk s of row r stored/read at s ^ (r&3) (4 chunks/row).
// MODE 0: fused QKV projection (bf16 routed out), grid 384 (8 XCD stripes)
// MODE 2: causal QK^T (fp16 scores out), triangular grid 144
template <int MODE>
__global__ __launch_bounds__(512)
void gemm8(const ushort_t* __restrict__ A, long long strideA,
           const ushort_t* __restrict__ Bt, long long strideB,
           const float* __restrict__ bq, const float* __restrict__ bk,
           const float* __restrict__ bv,
           ushort_t* __restrict__ Qb, ushort_t* __restrict__ Kb,
           ushort_t* __restrict__ Vt,
           ushort_t* __restrict__ Sh, int ldc, long long strideC)
{
    int bx, by, bz = 0;
    int f = blockIdx.x;
    if constexpr (MODE == 0) {
        // 384 = 8 XCDs * 48; each XCD owns a 4-row M-stripe x all 12 bx
        int xcd = f & 7, i = f >> 3;
        by = xcd * 4 + i / 12;                 // 32 M-tiles
        bx = i % 12;                           // 12 N-tiles of 256
    } else {
        int swz = (f & 7) * 18 + (f >> 3);     // 144 = 8*18 bijective
        bz = swz / 36; int t = swz % 36;
        int r = 0;
        while ((r + 1) * (r + 2) / 2 <= t) ++r;
        by = r; bx = t - r * (r + 1) / 2;      // lower triangle 8x8
    }

    const int tid = threadIdx.x;
    const int lane = tid & 63, wid = tid >> 6;
    const int wm = wid >> 2, wc = wid & 3;     // 2M x 4N waves
    const int frow = lane & 15, fq4 = lane >> 4;

    const ushort_t* Ab = A + (size_t)bz * strideA;
    const ushort_t* Bb = Bt + (size_t)bz * strideB;
    const int brow = by * 256, bcol = bx * 256;

    __shared__ ushort_t LA[2][2][256 * 32];    // [buf][khalf] 4 x 16 KB
    __shared__ ushort_t LB[2][2][256 * 32];    // 4 x 16 KB  (total 128 KB)

    v4f acc[8][4];
    #pragma unroll
    for (int mi = 0; mi < 8; ++mi)
        #pragma unroll
        for (int ni = 0; ni < 4; ++ni)
            acc[mi][ni] = (v4f)0.f;

    const int srr = tid >> 2, sch = tid & 3;
    // stage one 16 KB half-tile: 2 x 16B/thread, LDS dest linear,
    // global source chunk pre-swizzled ch ^ (r&3)
    auto ST = [&](ushort_t* dst, const ushort_t* src, int grow0, int t, int kh) {
        #pragma unroll
        for (int c = 0; c < 2; ++c) {
            int r = c * 128 + srr;
            int ch = sch ^ (r & 3);
            load_lds16(src + (size_t)(grow0 + r) * 1024 + t * 64 + kh * 32 + ch * 8,
                       dst + (size_t)(c * 128 + srr) * 32 + sch * 8);
        }
    };

    v8s a[4], b[4];
    auto RDA = [&](int buf, int kh, int mh) {
        #pragma unroll
        for (int i = 0; i < 4; ++i) {
            int r = wm * 128 + (mh * 4 + i) * 16 + frow;
            a[i] = *(const v8s*)(&LA[buf][kh][(size_t)r * 32 + ((fq4 ^ (frow & 3)) * 8)]);
        }
    };
    auto RDB = [&](int buf, int kh) {
        #pragma unroll
        for (int i = 0; i < 4; ++i) {
            int r = wc * 64 + i * 16 + frow;
            b[i] = *(const v8s*)(&LB[buf][kh][(size_t)r * 32 + ((fq4 ^ (frow & 3)) * 8)]);
        }
    };
    auto MM = [&](int mh) {
        __builtin_amdgcn_s_setprio(1);
        #pragma unroll
        for (int i = 0; i < 4; ++i)
            #pragma unroll
            for (int n = 0; n < 4; ++n)
                acc[mh * 4 + i][n] =
                    __builtin_amdgcn_mfma_f32_16x16x32_bf16(a[i], b[n], acc[mh * 4 + i][n], 0, 0, 0);
        __builtin_amdgcn_s_setprio(0);
    };

    // prologue: t0=0 fully, t1=1 K-half0; vmcnt(4) leaves t1-kh0 in flight
    ST(LA[0][0], Ab, brow, 0, 0); ST(LB[0][0], Bb, bcol, 0, 0);
    ST(LA[0][1], Ab, brow, 0, 1); ST(LB[0][1], Bb, bcol, 0, 1);
    ST(LA[1][0], Ab, brow, 1, 0); ST(LB[1][0], Bb, bcol, 1, 0);
    VMC(4); BAR();

    for (int u = 0; u < 8; ++u) {
        const int t0 = 2 * u, t1 = 2 * u + 1;
        const bool pf = (u < 7);
        // ph1: t0 kh0 mh0
        RDA(0, 0, 0); RDB(0, 0); ST(LA[1][1], Ab, brow, t1, 1);
        BAR(); LGKM0(); MM(0); BAR();
        // ph2: t0 kh0 mh1 (b held)
        RDA(0, 0, 1); ST(LB[1][1], Bb, bcol, t1, 1);
        BAR(); LGKM0(); MM(1); BAR();
        // ph3: t0 kh1 mh0
        RDA(0, 1, 0); RDB(0, 1); if (pf) ST(LA[0][0], Ab, brow, t0 + 2, 0);
        BAR(); LGKM0(); MM(0); BAR();
        // ph4: t0 kh1 mh1 + vmcnt
        RDA(0, 1, 1); if (pf) { ST(LB[0][0], Bb, bcol, t0 + 2, 0); VMC(4); }
        else VMC(0);
        BAR(); LGKM0(); MM(1); BAR();
        // ph5: t1 kh0 mh0
        RDA(1, 0, 0); RDB(1, 0); if (pf) ST(LA[0][1], Ab, brow, t0 + 2, 1);
        BAR(); LGKM0(); MM(0); BAR();
        // ph6: t1 kh0 mh1
        RDA(1, 0, 1); if (pf) ST(LB[0][1], Bb, bcol, t0 + 2, 1);
        BAR(); LGKM0(); MM(1); BAR();
        // ph7: t1 kh1 mh0
        RDA(1, 1, 0); RDB(1, 1); if (pf) ST(LA[1][0], Ab, brow, t1 + 2, 0);
        BAR(); LGKM0(); MM(0); BAR();
        // ph8: t1 kh1 mh1 + vmcnt
        RDA(1, 1, 1); if (pf) { ST(LB[1][0], Bb, bcol, t1 + 2, 0); VMC(4); }
        BAR(); LGKM0(); MM(1); BAR();
    }

    const int fr = lane & 15;
    const int fq = lane >> 4;

    if constexpr (MODE == 0) {
        const int route = bx >> 2;             // 0=Q, 1=K, 2=V (4 tiles each)
        const int cbase = (bx & 3) * 256 + wc * 64;
        if (route < 2) {
            ushort_t* C = route ? Kb : Qb;
            const float* bias = route ? bk : bq;
            const float scale = route ? 1.0f : 0.03125f;
            #pragma unroll
            for (int ni = 0; ni < 4; ++ni) {
                int cg = cbase + ni * 16 + fr;
                float bb = bias[cg];
                #pragma unroll
                for (int mi = 0; mi < 8; ++mi) {
                    int gr0 = brow + wm * 128 + mi * 16 + fq * 4;
                    #pragma unroll
                    for (int j = 0; j < 4; ++j)
                        C[(size_t)(gr0 + j) * 1024 + cg] = f2bf((acc[mi][ni][j] + bb) * scale);
                }
            }
        } else {
            #pragma unroll
            for (int ni = 0; ni < 4; ++ni) {
                int e = cbase + ni * 16 + fr;
                float bb = bv[e];
                #pragma unroll
                for (int mi = 0; mi < 8; ++mi) {
                    int gr0 = brow + wm * 128 + mi * 16 + fq * 4;   // b*2048+s
                    int bbat = gr0 >> 11;
                    int sl2 = gr0 & 2047;
                    alignas(8) ushort_t tmp[4];
                    #pragma unroll
                    for (int j = 0; j < 4; ++j)
                        tmp[j] = f2bf(acc[mi][ni][j] + bb);
                    *(v4s*)(Vt + (size_t)bbat * (1024 * 2048) + (size_t)e * 2048 + sl2) =
                        *(const v4s*)tmp;
                }
            }
        }
    } else {
        ushort_t* C = Sh + (size_t)bz * strideC;
        #pragma unroll
        for (int ni = 0; ni < 4; ++ni) {
            int gc = bcol + wc * 64 + ni * 16 + fr;
            #pragma unroll
            for (int mi = 0; mi < 8; ++mi) {
                int gr0 = brow + wm * 128 + mi * 16 + fq * 4;
                #pragma unroll
                for (int j = 0; j < 4; ++j)
                    C[(size_t)(gr0 + j) * ldc + gc] = f2h(acc[mi][ni][j]);
            }
        }
    }
}

// ---------------------------------------------------------------------------
// PV: r10-proven single-barrier ring-3, 256 thr, 128x128 tile, BK=32,
// counted vmcnt(4)/0, kEnd=(by+1)*128, grid 512 LPT.
__global__ __launch_bounds__(256)
void gemm_pv(const ushort_t* __restrict__ A, int lda, long long strideA,
             const ushort_t* __restrict__ Bt, int ldb, long long strideB,
             float* __restrict__ Cout, int ldc, long long strideC, int K)
{
    int f = blockIdx.x;
    int swz = (f & 7) * 64 + (f >> 3);         // 512 = 8*64 bijective
    int bz = swz >> 7; int rem = swz & 127;
    int by = 15 - (rem >> 3), bx = rem & 7;    // long (high-K) blocks first

    const int tid = threadIdx.x;
    const int lane = tid & 63, wid = tid >> 6;
    const int wm = wid >> 1, wc = wid & 1;

    const ushort_t* Ab = A + (size_t)bz * strideA;
    const ushort_t* Bb = Bt + (size_t)bz * strideB;

    __shared__ ushort_t As[3][128 * 32];
    __shared__ ushort_t Bs[3][128 * 32];

    const int brow = by * 128, bcol = bx * 128;
    int kEnd = (by + 1) * 128; if (kEnd > K) kEnd = K;
    const int nt = kEnd / 32;

    v4f acc[4][4];
    #pragma unroll
    for (int mi = 0; mi < 4; ++mi)
        #pragma unroll
        for (int ni = 0; ni < 4; ++ni)
            acc[mi][ni] = (v4f)0.f;

    const int rr = tid >> 2, slot = tid & 3;
    auto STAGE = [&](int buf, int t) {
        const int k0 = t * 32;
        #pragma unroll
        for (int c = 0; c < 2; ++c) {
            int r = c * 64 + rr;
            int sc = ((slot ^ ((r >> 1) & 3)) << 3);
            load_lds16(Ab + (size_t)(brow + r) * lda + k0 + sc,
                       &As[buf][(size_t)(c * 64 + wid * 16) * 32]);
        }
        #pragma unroll
        for (int c = 0; c < 2; ++c) {
            int r = c * 64 + rr;
            int sc = ((slot ^ ((r >> 1) & 3)) << 3);
            load_lds16(Bb + (size_t)(bcol + r) * ldb + k0 + sc,
                       &Bs[buf][(size_t)(c * 64 + wid * 16) * 32]);
        }
    };

    const int frow = lane & 15, fq4 = lane >> 4;
    const int csw = ((fq4 ^ ((frow >> 1) & 3)) << 3);

    STAGE(0, 0);
    if (nt > 1) STAGE(1, 1);

    int cur = 0;
    for (int t = 0; t < nt; ++t) {
        if (t + 1 < nt) VMC(4); else VMC(0);
        BAR();
        if (t + 2 < nt) {
            int tgt = cur ? cur - 1 : 2;
            STAGE(tgt, t + 2);
        }
        const ushort_t* Ac = &As[cur][0];
        const ushort_t* Bc = &Bs[cur][0];
        v8s a[4], b[4];
        #pragma unroll
        for (int mi = 0; mi < 4; ++mi)
            a[mi] = *(const v8s*)(Ac + (size_t)(wm * 64 + mi * 16 + frow) * 32 + csw);
        #pragma unroll
        for (int ni = 0; ni < 4; ++ni)
            b[ni] = *(const v8s*)(Bc + (size_t)(wc * 64 + ni * 16 + frow) * 32 + csw);
        __builtin_amdgcn_s_setprio(1);
        #pragma unroll
        for (int mi = 0; mi < 4; ++mi)
            #pragma unroll
            for (int ni = 0; ni < 4; ++ni)
                acc[mi][ni] = __builtin_amdgcn_mfma_f32_16x16x32_bf16(a[mi], b[ni], acc[mi][ni], 0, 0, 0);
        __builtin_amdgcn_s_setprio(0);
        cur = (cur == 2) ? 0 : cur + 1;
    }

    float* C = Cout + (size_t)bz * strideC;
    const int fr = lane & 15;
    const int fq = lane >> 4;
    #pragma unroll
    for (int ni = 0; ni < 4; ++ni) {
        int gc = bcol + wc * 64 + ni * 16 + fr;
        #pragma unroll
        for (int mi = 0; mi < 4; ++mi) {
            int gr0 = brow + wm * 64 + mi * 16 + fq * 4;
            #pragma unroll
            for (int j = 0; j < 4; ++j)
                C[(size_t)(gr0 + j) * ldc + gc] = acc[mi][ni][j];
        }
    }
}

// ---------------------------------------------------------------------------
// causal row softmax; fp16 scores row -> bf16 P in place (pitch 2048 elems).
// Writes zeros up to Lw = round-up-128(i+1) — PV K-limit granularity is 128.
__global__ __launch_bounds__(256) void softmax_causal(ushort_t* __restrict__ Sc) {
    int row = blockIdx.x;                // b*2048 + i
    int b = row >> 11, i = row & 2047;
    ushort_t* srow = Sc + ((size_t)b * 2048 + i) * 2048;
    const int L = i + 1;
    const int Lw = ((i >> 7) + 1) << 7;
    __shared__ float vals[2048];
    __shared__ float red[8];
    int tid = threadIdx.x, lane = tid & 63, wid = tid >> 6;

    float mx = -3.0e38f;
    const int L4 = L >> 2;
    for (int j4 = tid; j4 < L4; j4 += 256) {
        v4s u = *(const v4s*)(srow + j4 * 4);
        float4 v;
        v.x = h2f((unsigned short)u[0]); v.y = h2f((unsigned short)u[1]);
        v.z = h2f((unsigned short)u[2]); v.w = h2f((unsigned short)u[3]);
        ((float4*)vals)[j4] = v;
        mx = fmaxf(fmaxf(mx, fmaxf(v.x, v.y)), fmaxf(v.z, v.w));
    }
    {
        int j = (L4 << 2) + tid;
        if (j < L) { float v = h2f(srow[j]); vals[j] = v; mx = fmaxf(mx, v); }
    }
    #pragma unroll
    for (int o = 32; o; o >>= 1) mx = fmaxf(mx, __shfl_down(mx, o));
    if (lane == 0) red[wid] = mx;
    __syncthreads();
    mx = fmaxf(fmaxf(red[0], red[1]), fmaxf(red[2], red[3]));

    float sum = 0.f;
    for (int j = tid; j < L; j += 256) {
        float e = __expf(vals[j] - mx);
        vals[j] = e;
        sum += e;
    }
    #pragma unroll
    for (int o = 32; o; o >>= 1) sum += __shfl_down(sum, o);
    if (lane == 0) red[wid + 4] = sum;
    __syncthreads();
    float inv = 1.f / (red[4] + red[5] + red[6] + red[7]);

    for (int j4 = tid; j4 * 4 < Lw; j4 += 256) {
        int j = j4 * 4;
        float4 v = ((const float4*)vals)[j4];
        v4s p;
        p[0] = (short)f2bf((j     < L) ? v.x * inv : 0.f);
        p[1] = (short)f2bf((j + 1 < L) ? v.y * inv : 0.f);
        p[2] = (short)f2bf((j + 2 < L) ? v.z * inv : 0.f);
        p[3] = (short)f2bf((j + 3 < L) ? v.w * inv : 0.f);
        *(v4s*)(srow + j) = p;
    }
}

// ---------------------------------------------------------------------------
extern "C" void kernel_launch(void* const* d_in, const int* in_sizes, int n_in,
                              void* d_out, int out_size, void* d_ws, size_t ws_size,
                              hipStream_t stream) {
    const float* x  = (const float*)d_in[0];
    // d_in[1] = additive causal mask: structurally known, not read.
    const float* Wq = (const float*)d_in[2];
    const float* bq = (const float*)d_in[3];
    const float* Wk = (const float*)d_in[4];
    const float* bk = (const float*)d_in[5];
    const float* Wv = (const float*)d_in[6];
    const float* bv = (const float*)d_in[7];

    ushort_t* xb = (ushort_t*)d_ws;                        // 16.78 MB
    ushort_t* Wt = xb + (size_t)8192 * 1024;               //  6.29 MB (3x1024x1024)
    ushort_t* Qb = Wt + (size_t)3 * 1024 * 1024;           // 16.78 MB (scaled 1/32)
    ushort_t* Kb = Qb + (size_t)8192 * 1024;               // 16.78 MB
    ushort_t* Vt = Kb + (size_t)8192 * 1024;               // 16.78 MB (4x[1024][2048])
    ushort_t* Sc = Vt + (size_t)8192 * 1024;               // 33.55 MB (fp16 S / bf16 P)

    cvt_kernel<<<2048, 256, 0, stream>>>((const float4*)x, xb, 8192 * 1024 / 4);
    transpose_w<<<dim3(32, 32, 3), dim3(32, 8), 0, stream>>>(Wq, Wk, Wv, Wt);

    // fused QKV projection: [8192x1024] x [3072x1024]^T, 8-phase 256^2
    gemm8<0><<<384, 512, 0, stream>>>(xb, 0, Wt, 0,
                                      bq, bk, bv, Qb, Kb, Vt,
                                      nullptr, 0, 0);

    // scores = Q K^T (causal, 256^2 tiles, 144 blocks, fp16 out)
    gemm8<2><<<144, 512, 0, stream>>>(Qb, 2048LL * 1024, Kb, 2048LL * 1024,
                                      nullptr, nullptr, nullptr,
                                      nullptr, nullptr, nullptr,
                                      Sc, 2048, 2048LL * 2048);

    softmax_causal<<<8192, 256, 0, stream>>>(Sc);

    // O = P V (128x128 tiles, 512 blocks, K limited per 128-row block)
    gemm_pv<<<512, 256, 0, stream>>>(Sc, 2048, 2048LL * 2048,
                                     Vt, 2048, 2048LL * 1024,
                                     (float*)d_out, 1024, 2048LL * 1024, 2048);
    (void)in_sizes; (void)n_in; (void)out_size; (void)ws_size;
}

// Round 12
// 178.252 us; speedup vs baseline: 1.0242x; 1.0242x over previous
//
#include <hip/hip_runtime.h>
#include <hip/hip_bf16.h>
#include <hip/hip_fp16.h>
#include <math.h>

typedef short v8s __attribute__((ext_vector_type(8)));
typedef short v4s __attribute__((ext_vector_type(4)));
typedef float v4f __attribute__((ext_vector_type(4)));
typedef unsigned short ushort_t;

__device__ __forceinline__ unsigned short f2bf(float f) {
    unsigned int u = __float_as_uint(f);
    u = (u + 0x7FFFu + ((u >> 16) & 1u)) >> 16;   // RNE
    return (unsigned short)u;
}
__device__ __forceinline__ unsigned short f2h(float f) {
    __half h = __float2half(f);
    return *reinterpret_cast<unsigned short*>(&h);
}
__device__ __forceinline__ float h2f(unsigned short u) {
    __half h = *reinterpret_cast<__half*>(&u);
    return __half2float(h);
}

__device__ __forceinline__ void load_lds16(const void* g, void* l) {
    __builtin_amdgcn_global_load_lds((const __attribute__((address_space(1))) void*)g,
                                     (__attribute__((address_space(3))) void*)l,
                                     16, 0, 0);
}

#define FENCE() asm volatile("" ::: "memory")
#define BAR() do { FENCE(); __builtin_amdgcn_s_barrier(); FENCE(); } while (0)
#define LGKM0() asm volatile("s_waitcnt lgkmcnt(0)" ::: "memory")
#define VMC(n) asm volatile("s_waitcnt vmcnt(" #n ")" ::: "memory")

// ---------------------------------------------------------------------------
// Fused prep: blocks 0..2047 convert x fp32->bf16; blocks 2048..5119
// transpose the 3 projection weights to bf16 [3072][1024].
__global__ __launch_bounds__(256)
void prep_kernel(const float4* __restrict__ x4, ushort_t* __restrict__ xb,
                 const float* __restrict__ W0, const float* __restrict__ W1,
                 const float* __restrict__ W2, ushort_t* __restrict__ Wt) {
    if (blockIdx.x < 2048) {
        int i = blockIdx.x * 256 + threadIdx.x;
        #pragma unroll
        for (int it = 0; it < 4; ++it, i += 524288) {
            float4 v = x4[i];
            v4s p;
            p[0] = (short)f2bf(v.x); p[1] = (short)f2bf(v.y);
            p[2] = (short)f2bf(v.z); p[3] = (short)f2bf(v.w);
            *(v4s*)(xb + (size_t)i * 4) = p;
        }
    } else {
        int f = blockIdx.x - 2048;             // 0..3071
        int z = f >> 10; int rem = f & 1023;
        int n0 = (rem & 31) * 32, k0 = (rem >> 5) * 32;
        const float* W = (z == 0) ? W0 : (z == 1 ? W1 : W2);
        ushort_t* out = Wt + (size_t)z * 1024 * 1024;
        __shared__ float tile[32][33];
        int tx = threadIdx.x & 31, ty = threadIdx.x >> 5;   // 32 x 8
        #pragma unroll
        for (int i2 = 0; i2 < 32; i2 += 8)
            tile[ty + i2][tx] = W[(size_t)(k0 + ty + i2) * 1024 + n0 + tx];
        __syncthreads();
        #pragma unroll
        for (int i2 = 0; i2 < 32; i2 += 8)
            out[(size_t)(n0 + ty + i2) * 1024 + k0 + tx] = f2bf(tile[tx][ty + i2]);
    }
}

// ---------------------------------------------------------------------------
// 256x256-tile 8-phase QKV GEMM (m201-geometry; r11-correctness-verified,
// swizzle FIXED to the r7-proven (r>>1)&3 form). 512 thr, 8 waves (2Mx4N),
// acc 8x4 (64 MFMA/K-tile/wave). BK=64, LDS = 2buf x 2K-half x 256x32 x
// {A,B} = 128 KB. Phases: pre-barrier ds_reads, one half-tile stage, BAR,
// lgkmcnt(0), setprio(1), 16 MFMA, setprio(0), BAR. vmcnt(4) at ph4/ph8.
__global__ __launch_bounds__(512)
void gemm8_qkv(const ushort_t* __restrict__ A, const ushort_t* __restrict__ Bt,
               const float* __restrict__ bq, const float* __restrict__ bk,
               const float* __restrict__ bv,
               ushort_t* __restrict__ Qb, ushort_t* __restrict__ Kb,
               ushort_t* __restrict__ Vt)
{
    // 384 = 8 XCDs * 48; each XCD owns a 4-row M-stripe x all 12 bx
    int f = blockIdx.x;
    int xcd = f & 7, i = f >> 3;
    const int by = xcd * 4 + i / 12;           // 32 M-tiles
    const int bx = i % 12;                     // 12 N-tiles of 256

    const int tid = threadIdx.x;
    const int lane = tid & 63, wid = tid >> 6;
    const int wm = wid >> 2, wc = wid & 3;     // 2M x 4N waves
    const int frow = lane & 15, fq4 = lane >> 4;

    const int brow = by * 256, bcol = bx * 256;

    __shared__ ushort_t LA[2][2][256 * 32];    // [buf][khalf] 4 x 16 KB
    __shared__ ushort_t LB[2][2][256 * 32];    // 4 x 16 KB  (total 128 KB)

    v4f acc[8][4];
    #pragma unroll
    for (int mi = 0; mi < 8; ++mi)
        #pragma unroll
        for (int ni = 0; ni < 4; ++ni)
            acc[mi][ni] = (v4f)0.f;

    const int srr = tid >> 2, sch = tid & 3;
    // stage one 16 KB half-tile: 2 x 16B/thread, LDS dest linear,
    // global source chunk pre-swizzled ch ^ ((r>>1)&3)   [r7-proven]
    auto ST = [&](ushort_t* dst, const ushort_t* src, int grow0, int t, int kh) {
        #pragma unroll
        for (int c = 0; c < 2; ++c) {
            int r = c * 128 + srr;
            int ch = sch ^ ((r >> 1) & 3);
            load_lds16(src + (size_t)(grow0 + r) * 1024 + t * 64 + kh * 32 + ch * 8,
                       dst + (size_t)(c * 128 + srr) * 32 + sch * 8);
        }
    };

    v8s a[4], b[4];
    const int rsw = fq4 ^ ((frow >> 1) & 3);   // read-side chunk swizzle
    auto RDA = [&](int buf, int kh, int mh) {
        #pragma unroll
        for (int i2 = 0; i2 < 4; ++i2) {
            int r = wm * 128 + (mh * 4 + i2) * 16 + frow;
            a[i2] = *(const v8s*)(&LA[buf][kh][(size_t)r * 32 + rsw * 8]);
        }
    };
    auto RDB = [&](int buf, int kh) {
        #pragma unroll
        for (int i2 = 0; i2 < 4; ++i2) {
            int r = wc * 64 + i2 * 16 + frow;
            b[i2] = *(const v8s*)(&LB[buf][kh][(size_t)r * 32 + rsw * 8]);
        }
    };
    auto MM = [&](int mh) {
        __builtin_amdgcn_s_setprio(1);
        #pragma unroll
        for (int i2 = 0; i2 < 4; ++i2)
            #pragma unroll
            for (int n = 0; n < 4; ++n)
                acc[mh * 4 + i2][n] =
                    __builtin_amdgcn_mfma_f32_16x16x32_bf16(a[i2], b[n], acc[mh * 4 + i2][n], 0, 0, 0);
        __builtin_amdgcn_s_setprio(0);
    };

    // prologue: t0=0 fully, t1=1 K-half0; vmcnt(4) leaves t1-kh0 in flight
    ST(LA[0][0], A, brow, 0, 0); ST(LB[0][0], Bt, bcol, 0, 0);
    ST(LA[0][1], A, brow, 0, 1); ST(LB[0][1], Bt, bcol, 0, 1);
    ST(LA[1][0], A, brow, 1, 0); ST(LB[1][0], Bt, bcol, 1, 0);
    VMC(4); BAR();

    for (int u = 0; u < 8; ++u) {
        const int t0 = 2 * u, t1 = 2 * u + 1;
        const bool pf = (u < 7);
        // ph1: t0 kh0 mh0
        RDA(0, 0, 0); RDB(0, 0); ST(LA[1][1], A, brow, t1, 1);
        BAR(); LGKM0(); MM(0); BAR();
        // ph2: t0 kh0 mh1 (b held)
        RDA(0, 0, 1); ST(LB[1][1], Bt, bcol, t1, 1);
        BAR(); LGKM0(); MM(1); BAR();
        // ph3: t0 kh1 mh0
        RDA(0, 1, 0); RDB(0, 1); if (pf) ST(LA[0][0], A, brow, t0 + 2, 0);
        BAR(); LGKM0(); MM(0); BAR();
        // ph4: t0 kh1 mh1 + vmcnt
        RDA(0, 1, 1); if (pf) { ST(LB[0][0], Bt, bcol, t0 + 2, 0); VMC(4); }
        else VMC(0);
        BAR(); LGKM0(); MM(1); BAR();
        // ph5: t1 kh0 mh0
        RDA(1, 0, 0); RDB(1, 0); if (pf) ST(LA[0][1], A, brow, t0 + 2, 1);
        BAR(); LGKM0(); MM(0); BAR();
        // ph6: t1 kh0 mh1
        RDA(1, 0, 1); if (pf) ST(LB[0][1], Bt, bcol, t0 + 2, 1);
        BAR(); LGKM0(); MM(1); BAR();
        // ph7: t1 kh1 mh0
        RDA(1, 1, 0); RDB(1, 1); if (pf) ST(LA[1][0], A, brow, t1 + 2, 0);
        BAR(); LGKM0(); MM(0); BAR();
        // ph8: t1 kh1 mh1 + vmcnt
        RDA(1, 1, 1); if (pf) { ST(LB[1][0], Bt, bcol, t1 + 2, 0); VMC(4); }
        BAR(); LGKM0(); MM(1); BAR();
    }

    const int fr = lane & 15;
    const int fq = lane >> 4;
    const int route = bx >> 2;                 // 0=Q, 1=K, 2=V (4 tiles each)
    const int cbase = (bx & 3) * 256 + wc * 64;
    if (route < 2) {
        ushort_t* C = route ? Kb : Qb;
        const float* bias = route ? bk : bq;
        const float scale = route ? 1.0f : 0.03125f;
        #pragma unroll
        for (int ni = 0; ni < 4; ++ni) {
            int cg = cbase + ni * 16 + fr;
            float bb = bias[cg];
            #pragma unroll
            for (int mi = 0; mi < 8; ++mi) {
                int gr0 = brow + wm * 128 + mi * 16 + fq * 4;
                #pragma unroll
                for (int j = 0; j < 4; ++j)
                    C[(size_t)(gr0 + j) * 1024 + cg] = f2bf((acc[mi][ni][j] + bb) * scale);
            }
        }
    } else {
        #pragma unroll
        for (int ni = 0; ni < 4; ++ni) {
            int e = cbase + ni * 16 + fr;
            float bb = bv[e];
            #pragma unroll
            for (int mi = 0; mi < 8; ++mi) {
                int gr0 = brow + wm * 128 + mi * 16 + fq * 4;   // b*2048+s
                int bbat = gr0 >> 11;
                int sl2 = gr0 & 2047;
                alignas(8) ushort_t tmp[4];
                #pragma unroll
                for (int j = 0; j < 4; ++j)
                    tmp[j] = f2bf(acc[mi][ni][j] + bb);
                *(v4s*)(Vt + (size_t)bbat * (1024 * 2048) + (size_t)e * 2048 + sl2) =
                    *(const v4s*)tmp;
            }
        }
    }
}

// ---------------------------------------------------------------------------
// r10-proven single-barrier ring-3 GEMM.
// MODE 2: causal QK^T, 512 thr, 128x256, grid 288, fp16 scores out
// MODE 3: PV, 256 thr, 128x128, grid 512, kEnd=(by+1)*128, LPT order
template <int MODE>
__global__ __launch_bounds__(MODE == 3 ? 256 : 512)
void gemm_ring(const ushort_t* __restrict__ A, int lda, long long strideA,
               const ushort_t* __restrict__ Bt, int ldb, long long strideB,
               void* __restrict__ Cv, int ldc, long long strideC, int K)
{
    constexpr int THREADS = (MODE == 3) ? 256 : 512;
    constexpr int BN      = (MODE == 3) ? 128 : 256;
    constexpr int NW      = THREADS / 64;
    constexpr int RPL     = THREADS / 4;
    constexpr int ALINES  = 128 / RPL;
    constexpr int BLINES  = BN / RPL;
    constexpr int LOADS   = ALINES + BLINES;

    int bx, by, bz;
    int f = blockIdx.x;
    if constexpr (MODE == 2) {
        int swz = (f & 7) * 36 + (f >> 3);     // 288 = 8*36 bijective
        bz = swz / 72; int t = swz % 72;
        int r = 0, c = 0;
        while (c + (r / 2 + 1) <= t) { c += r / 2 + 1; ++r; }
        by = r; bx = t - c;                    // cols per row-block: by/2+1
    } else {
        int swz = (f & 7) * 64 + (f >> 3);     // 512 = 8*64 bijective
        bz = swz >> 7; int rem = swz & 127;
        by = 15 - (rem >> 3); bx = rem & 7;    // long (high-K) blocks first
    }

    const int tid = threadIdx.x;
    const int lane = tid & 63, wid = tid >> 6;
    const int wm = (NW == 8) ? (wid >> 2) : (wid >> 1);
    const int wc = wid & ((NW == 8) ? 3 : 1);

    const ushort_t* Ab = A + (size_t)bz * strideA;
    const ushort_t* Bb = Bt + (size_t)bz * strideB;

    __shared__ ushort_t As[3][128 * 32];
    __shared__ ushort_t Bs[3][BN * 32];

    const int brow = by * 128, bcol = bx * BN;

    int kEnd = K;
    if constexpr (MODE == 3) { int lim = (by + 1) * 128; kEnd = lim < K ? lim : K; }
    const int nt = kEnd / 32;

    v4f acc[4][4];
    #pragma unroll
    for (int mi = 0; mi < 4; ++mi)
        #pragma unroll
        for (int ni = 0; ni < 4; ++ni)
            acc[mi][ni] = (v4f)0.f;

    const int rr = tid >> 2, slot = tid & 3;
    auto STAGE = [&](int buf, int t) {
        const int k0 = t * 32;
        #pragma unroll
        for (int c = 0; c < ALINES; ++c) {
            int r = c * RPL + rr;
            int sc = ((slot ^ ((r >> 1) & 3)) << 3);
            load_lds16(Ab + (size_t)(brow + r) * lda + k0 + sc,
                       &As[buf][(size_t)(c * RPL + wid * 16) * 32]);
        }
        #pragma unroll
        for (int c = 0; c < BLINES; ++c) {
            int r = c * RPL + rr;
            int sc = ((slot ^ ((r >> 1) & 3)) << 3);
            load_lds16(Bb + (size_t)(bcol + r) * ldb + k0 + sc,
                       &Bs[buf][(size_t)(c * RPL + wid * 16) * 32]);
        }
    };

    const int frow = lane & 15, fq4 = lane >> 4;
    const int csw = ((fq4 ^ ((frow >> 1) & 3)) << 3);

    STAGE(0, 0);
    if (nt > 1) STAGE(1, 1);

    int cur = 0;
    for (int t = 0; t < nt; ++t) {
        if (t + 1 < nt) {
            asm volatile("s_waitcnt vmcnt(%0)" :: "i"(LOADS) : "memory");
        } else {
            asm volatile("s_waitcnt vmcnt(0)" ::: "memory");
        }
        BAR();
        if (t + 2 < nt) {
            int tgt = cur ? cur - 1 : 2;
            STAGE(tgt, t + 2);
        }
        const ushort_t* Ac = &As[cur][0];
        const ushort_t* Bc = &Bs[cur][0];
        v8s a[4], b[4];
        #pragma unroll
        for (int mi = 0; mi < 4; ++mi)
            a[mi] = *(const v8s*)(Ac + (size_t)(wm * 64 + mi * 16 + frow) * 32 + csw);
        #pragma unroll
        for (int ni = 0; ni < 4; ++ni)
            b[ni] = *(const v8s*)(Bc + (size_t)(wc * 64 + ni * 16 + frow) * 32 + csw);
        __builtin_amdgcn_s_setprio(1);
        #pragma unroll
        for (int mi = 0; mi < 4; ++mi)
            #pragma unroll
            for (int ni = 0; ni < 4; ++ni)
                acc[mi][ni] = __builtin_amdgcn_mfma_f32_16x16x32_bf16(a[mi], b[ni], acc[mi][ni], 0, 0, 0);
        __builtin_amdgcn_s_setprio(0);
        cur = (cur == 2) ? 0 : cur + 1;
    }

    const int fr = lane & 15;
    const int fq = lane >> 4;
    if constexpr (MODE == 2) {
        ushort_t* C = (ushort_t*)Cv + (size_t)bz * strideC;
        #pragma unroll
        for (int ni = 0; ni < 4; ++ni) {
            int gc = bcol + wc * 64 + ni * 16 + fr;
            #pragma unroll
            for (int mi = 0; mi < 4; ++mi) {
                int gr0 = brow + wm * 64 + mi * 16 + fq * 4;
                #pragma unroll
                for (int j = 0; j < 4; ++j)
                    C[(size_t)(gr0 + j) * ldc + gc] = f2h(acc[mi][ni][j]);
            }
        }
    } else {
        float* C = (float*)Cv + (size_t)bz * strideC;
        #pragma unroll
        for (int ni = 0; ni < 4; ++ni) {
            int gc = bcol + wc * 64 + ni * 16 + fr;
            #pragma unroll
            for (int mi = 0; mi < 4; ++mi) {
                int gr0 = brow + wm * 64 + mi * 16 + fq * 4;
                #pragma unroll
                for (int j = 0; j < 4; ++j)
                    C[(size_t)(gr0 + j) * ldc + gc] = acc[mi][ni][j];
            }
        }
    }
}

// ---------------------------------------------------------------------------
// causal row softmax, wave-per-row (no cross-wave sync): 2048 blocks x 4
// waves. fp16 scores -> bf16 P in place; zeros up to Lw = roundup128(i+1).
__global__ __launch_bounds__(256) void softmax_causal(ushort_t* __restrict__ Sc) {
    __shared__ float vals[4][2048];
    const int wid = threadIdx.x >> 6, lane = threadIdx.x & 63;
    const int row = blockIdx.x * 4 + wid;    // b*2048 + i
    const int b = row >> 11, i = row & 2047;
    ushort_t* srow = Sc + ((size_t)b * 2048 + i) * 2048;
    const int L = i + 1;
    const int Lw = ((i >> 7) + 1) << 7;
    float* v = vals[wid];

    float mx = -3.0e38f;
    const int L4 = L >> 2;
    for (int j4 = lane; j4 < L4; j4 += 64) {
        v4s u = *(const v4s*)(srow + j4 * 4);
        float4 w;
        w.x = h2f((unsigned short)u[0]); w.y = h2f((unsigned short)u[1]);
        w.z = h2f((unsigned short)u[2]); w.w = h2f((unsigned short)u[3]);
        ((float4*)v)[j4] = w;
        mx = fmaxf(fmaxf(mx, fmaxf(w.x, w.y)), fmaxf(w.z, w.w));
    }
    {
        int j = (L4 << 2) + lane;
        if (j < L) { float t = h2f(srow[j]); v[j] = t; mx = fmaxf(mx, t); }
    }
    #pragma unroll
    for (int o = 32; o; o >>= 1) mx = fmaxf(mx, __shfl_xor(mx, o));

    float sum = 0.f;
    for (int j = lane; j < L; j += 64) {
        float e = __expf(v[j] - mx);
        v[j] = e;
        sum += e;
    }
    #pragma unroll
    for (int o = 32; o; o >>= 1) sum += __shfl_xor(sum, o);
    float inv = 1.f / sum;

    for (int j4 = lane; j4 * 4 < Lw; j4 += 64) {
        int j = j4 * 4;
        float4 w = ((const float4*)v)[j4];
        v4s p;
        p[0] = (short)f2bf((j     < L) ? w.x * inv : 0.f);
        p[1] = (short)f2bf((j + 1 < L) ? w.y * inv : 0.f);
        p[2] = (short)f2bf((j + 2 < L) ? w.z * inv : 0.f);
        p[3] = (short)f2bf((j + 3 < L) ? w.w * inv : 0.f);
        *(v4s*)(srow + j) = p;
    }
}

// ---------------------------------------------------------------------------
extern "C" void kernel_launch(void* const* d_in, const int* in_sizes, int n_in,
                              void* d_out, int out_size, void* d_ws, size_t ws_size,
                              hipStream_t stream) {
    const float* x  = (const float*)d_in[0];
    // d_in[1] = additive causal mask: structurally known, not read.
    const float* Wq = (const float*)d_in[2];
    const float* bq = (const float*)d_in[3];
    const float* Wk = (const float*)d_in[4];
    const float* bk = (const float*)d_in[5];
    const float* Wv = (const float*)d_in[6];
    const float* bv = (const float*)d_in[7];

    ushort_t* xb = (ushort_t*)d_ws;                        // 16.78 MB
    ushort_t* Wt = xb + (size_t)8192 * 1024;               //  6.29 MB (3x1024x1024)
    ushort_t* Qb = Wt + (size_t)3 * 1024 * 1024;           // 16.78 MB (scaled 1/32)
    ushort_t* Kb = Qb + (size_t)8192 * 1024;               // 16.78 MB
    ushort_t* Vt = Kb + (size_t)8192 * 1024;               // 16.78 MB (4x[1024][2048])
    ushort_t* Sc = Vt + (size_t)8192 * 1024;               // 33.55 MB (fp16 S / bf16 P)

    // prep: x->bf16 + W transpose in one dispatch
    prep_kernel<<<5120, 256, 0, stream>>>((const float4*)x, xb, Wq, Wk, Wv, Wt);

    // fused QKV projection: 8-phase 256^2, fixed swizzle
    gemm8_qkv<<<384, 512, 0, stream>>>(xb, Wt, bq, bk, bv, Qb, Kb, Vt);

    // scores = Q K^T (causal, 128x256 tiles, 288 blocks, fp16 out)
    gemm_ring<2><<<288, 512, 0, stream>>>(Qb, 1024, 2048LL * 1024,
                                          Kb, 1024, 2048LL * 1024,
                                          Sc, 2048, 2048LL * 2048, 1024);

    softmax_causal<<<2048, 256, 0, stream>>>(Sc);

    // O = P V (128x128 tiles, 512 blocks, K limited per 128-row block)
    gemm_ring<3><<<512, 256, 0, stream>>>(Sc, 2048, 2048LL * 2048,
                                          Vt, 2048, 2048LL * 1024,
                                          d_out, 1024, 2048LL * 1024, 2048);
    (void)in_sizes; (void)n_in; (void)out_size; (void)ws_size;
}

// Round 13
// 169.268 us; speedup vs baseline: 1.0785x; 1.0531x over previous
//
#include <hip/hip_runtime.h>
#include <hip/hip_bf16.h>
#include <hip/hip_fp16.h>
#include <math.h>

typedef short v8s __attribute__((ext_vector_type(8)));
typedef short v4s __attribute__((ext_vector_type(4)));
typedef float v4f __attribute__((ext_vector_type(4)));
typedef unsigned short ushort_t;

__device__ __forceinline__ unsigned short f2bf(float f) {
    unsigned int u = __float_as_uint(f);
    u = (u + 0x7FFFu + ((u >> 16) & 1u)) >> 16;   // RNE
    return (unsigned short)u;
}
__device__ __forceinline__ unsigned short f2h(float f) {
    __half h = __float2half(f);
    return *reinterpret_cast<unsigned short*>(&h);
}
__device__ __forceinline__ float h2f(unsigned short u) {
    __half h = *reinterpret_cast<__half*>(&u);
    return __half2float(h);
}

__device__ __forceinline__ void load_lds16(const void* g, void* l) {
    __builtin_amdgcn_global_load_lds((const __attribute__((address_space(1))) void*)g,
                                     (__attribute__((address_space(3))) void*)l,
                                     16, 0, 0);
}

#define FENCE() asm volatile("" ::: "memory")
#define BAR() do { FENCE(); __builtin_amdgcn_s_barrier(); FENCE(); } while (0)
#define LGKM0() asm volatile("s_waitcnt lgkmcnt(0)" ::: "memory")
#define VMC(n) asm volatile("s_waitcnt vmcnt(" #n ")" ::: "memory")

// ---------------------------------------------------------------------------
// Fused prep: blocks 0..2047 convert x fp32->bf16; blocks 2048..5119
// transpose the 3 projection weights to bf16 [3072][1024].
__global__ __launch_bounds__(256)
void prep_kernel(const float4* __restrict__ x4, ushort_t* __restrict__ xb,
                 const float* __restrict__ W0, const float* __restrict__ W1,
                 const float* __restrict__ W2, ushort_t* __restrict__ Wt) {
    if (blockIdx.x < 2048) {
        int i = blockIdx.x * 256 + threadIdx.x;
        #pragma unroll
        for (int it = 0; it < 4; ++it, i += 524288) {
            float4 v = x4[i];
            v4s p;
            p[0] = (short)f2bf(v.x); p[1] = (short)f2bf(v.y);
            p[2] = (short)f2bf(v.z); p[3] = (short)f2bf(v.w);
            *(v4s*)(xb + (size_t)i * 4) = p;
        }
    } else {
        int f = blockIdx.x - 2048;             // 0..3071
        int z = f >> 10; int rem = f & 1023;
        int n0 = (rem & 31) * 32, k0 = (rem >> 5) * 32;
        const float* W = (z == 0) ? W0 : (z == 1 ? W1 : W2);
        ushort_t* out = Wt + (size_t)z * 1024 * 1024;
        __shared__ float tile[32][33];
        int tx = threadIdx.x & 31, ty = threadIdx.x >> 5;   // 32 x 8
        #pragma unroll
        for (int i2 = 0; i2 < 32; i2 += 8)
            tile[ty + i2][tx] = W[(size_t)(k0 + ty + i2) * 1024 + n0 + tx];
        __syncthreads();
        #pragma unroll
        for (int i2 = 0; i2 < 32; i2 += 8)
            out[(size_t)(n0 + ty + i2) * 1024 + k0 + tx] = f2bf(tile[tx][ty + i2]);
    }
}

// ---------------------------------------------------------------------------
// 256x192-tile 8-phase QKV GEMM (r12 ledger, tail-free grid 512 = 2.0 exact
// rounds on 256 CUs). 512 thr, 8 waves (2Mx4N), per-wave 128x48 (acc 8x3).
// BK=64, LDS = LA 2x2x256x32 (64KB) + LB 2x2x192x32 (48KB) = 112 KB.
// B half-tiles (12KB = 768 chunks) staged by waves 0-5 only (tid<384,
// wave-uniform) -> per-wave vmcnt classes: w0-5 VMC(4), w6-7 VMC(2)
// (w6-7 issue only A loads; ledger re-derived per class, same ordering).
__global__ __launch_bounds__(512)
void gemm8_qkv(const ushort_t* __restrict__ A, const ushort_t* __restrict__ Bt,
               const float* __restrict__ bq, const float* __restrict__ bk,
               const float* __restrict__ bv,
               ushort_t* __restrict__ Qb, ushort_t* __restrict__ Kb,
               ushort_t* __restrict__ Vt)
{
    // 512 = 8 XCDs * 64; each XCD owns a 4-row M-stripe x all 16 bx
    int f = blockIdx.x;
    int xcd = f & 7, i = f >> 3;               // i 0..63
    const int by = xcd * 4 + (i >> 4);         // 32 M-tiles
    const int bx = i & 15;                     // 16 N-tiles of 192

    const int tid = threadIdx.x;
    const int lane = tid & 63, wid = tid >> 6;
    const int wm = wid >> 2, wc = wid & 3;     // 2M x 4N waves
    const int frow = lane & 15, fq4 = lane >> 4;
    const bool bstager = (wid < 6);            // waves 0-5 stage B

    const int brow = by * 256, bcol = bx * 192;

    __shared__ ushort_t LA[2][2][256 * 32];    // 4 x 16 KB
    __shared__ ushort_t LB[2][2][192 * 32];    // 4 x 12 KB   (112 KB total)

    v4f acc[8][3];
    #pragma unroll
    for (int mi = 0; mi < 8; ++mi)
        #pragma unroll
        for (int ni = 0; ni < 3; ++ni)
            acc[mi][ni] = (v4f)0.f;

    const int srr = tid >> 2, sch = tid & 3;
    // A half-tile: 16 KB = 1024 chunks, 2/thread (all waves)
    auto STA = [&](ushort_t* dst, int t, int kh) {
        #pragma unroll
        for (int c = 0; c < 2; ++c) {
            int r = c * 128 + srr;
            int ch = sch ^ ((r >> 1) & 3);
            load_lds16(A + (size_t)(brow + r) * 1024 + t * 64 + kh * 32 + ch * 8,
                       dst + (size_t)(c * 128 + srr) * 32 + sch * 8);
        }
    };
    // B half-tile: 12 KB = 768 chunks, 2/thread for tid<384 (waves 0-5)
    auto STB = [&](ushort_t* dst, int t, int kh) {
        if (bstager) {
            #pragma unroll
            for (int c = 0; c < 2; ++c) {
                int ck = c * 384 + tid;        // chunk 0..767
                int r = ck >> 2, s = ck & 3;
                int ch = s ^ ((r >> 1) & 3);
                load_lds16(Bt + (size_t)(bcol + r) * 1024 + t * 64 + kh * 32 + ch * 8,
                           dst + (size_t)ck * 8);
            }
        }
    };

    v8s a[4], b[3];
    const int rsw = fq4 ^ ((frow >> 1) & 3);
    auto RDA = [&](int buf, int kh, int mh) {
        #pragma unroll
        for (int i2 = 0; i2 < 4; ++i2) {
            int r = wm * 128 + (mh * 4 + i2) * 16 + frow;
            a[i2] = *(const v8s*)(&LA[buf][kh][(size_t)r * 32 + rsw * 8]);
        }
    };
    auto RDB = [&](int buf, int kh) {
        #pragma unroll
        for (int i2 = 0; i2 < 3; ++i2) {
            int r = wc * 48 + i2 * 16 + frow;
            b[i2] = *(const v8s*)(&LB[buf][kh][(size_t)r * 32 + rsw * 8]);
        }
    };
    auto MM = [&](int mh) {
        __builtin_amdgcn_s_setprio(1);
        #pragma unroll
        for (int i2 = 0; i2 < 4; ++i2)
            #pragma unroll
            for (int n = 0; n < 3; ++n)
                acc[mh * 4 + i2][n] =
                    __builtin_amdgcn_mfma_f32_16x16x32_bf16(a[i2], b[n], acc[mh * 4 + i2][n], 0, 0, 0);
        __builtin_amdgcn_s_setprio(0);
    };
    // per-wave-class counted wait: keep 2 stages (w0-5: 4 loads, w6-7: 2)
    auto WAIT2 = [&]() { if (bstager) { VMC(4); } else { VMC(2); } };

    // prologue: t0=0 fully, t1=1 K-half0 (order: LA00 LB00 LA01 LB01 LA10 LB10)
    STA(LA[0][0], 0, 0); STB(LB[0][0], 0, 0);
    STA(LA[0][1], 0, 1); STB(LB[0][1], 0, 1);
    STA(LA[1][0], 1, 0); STB(LB[1][0], 1, 0);
    WAIT2(); BAR();

    for (int u = 0; u < 8; ++u) {
        const int t0 = 2 * u, t1 = 2 * u + 1;
        const bool pf = (u < 7);
        // ph1: t0 kh0 mh0
        RDA(0, 0, 0); RDB(0, 0); STA(LA[1][1], t1, 1);
        BAR(); LGKM0(); MM(0); BAR();
        // ph2: t0 kh0 mh1 (b held)
        RDA(0, 0, 1); STB(LB[1][1], t1, 1);
        BAR(); LGKM0(); MM(1); BAR();
        // ph3: t0 kh1 mh0
        RDA(0, 1, 0); RDB(0, 1); if (pf) STA(LA[0][0], t0 + 2, 0);
        BAR(); LGKM0(); MM(0); BAR();
        // ph4: t0 kh1 mh1 + wait
        RDA(0, 1, 1);
        if (pf) { STB(LB[0][0], t0 + 2, 0); WAIT2(); }
        else    { VMC(0); }
        BAR(); LGKM0(); MM(1); BAR();
        // ph5: t1 kh0 mh0
        RDA(1, 0, 0); RDB(1, 0); if (pf) STA(LA[0][1], t0 + 2, 1);
        BAR(); LGKM0(); MM(0); BAR();
        // ph6: t1 kh0 mh1
        RDA(1, 0, 1); if (pf) STB(LB[0][1], t0 + 2, 1);
        BAR(); LGKM0(); MM(1); BAR();
        // ph7: t1 kh1 mh0
        RDA(1, 1, 0); RDB(1, 1); if (pf) STA(LA[1][0], t1 + 2, 0);
        BAR(); LGKM0(); MM(0); BAR();
        // ph8: t1 kh1 mh1 + wait
        RDA(1, 1, 1); if (pf) { STB(LB[1][0], t1 + 2, 0); WAIT2(); }
        BAR(); LGKM0(); MM(1); BAR();
    }

    const int fr = lane & 15;
    const int fq = lane >> 4;
    // per-ni routing: fragment base 16-aligned -> never straddles a
    // 1024-col boundary; route = gc>>10 (0=Q, 1=K, 2=V)
    #pragma unroll
    for (int ni = 0; ni < 3; ++ni) {
        int gc = bx * 192 + wc * 48 + ni * 16 + fr;
        int route = gc >> 10;
        int cg = gc & 1023;
        if (route < 2) {
            ushort_t* C = route ? Kb : Qb;
            float bb = (route ? bk : bq)[cg];
            float scale = route ? 1.0f : 0.03125f;
            #pragma unroll
            for (int mi = 0; mi < 8; ++mi) {
                int gr0 = brow + wm * 128 + mi * 16 + fq * 4;
                #pragma unroll
                for (int j = 0; j < 4; ++j)
                    C[(size_t)(gr0 + j) * 1024 + cg] = f2bf((acc[mi][ni][j] + bb) * scale);
            }
        } else {
            float bb = bv[cg];
            #pragma unroll
            for (int mi = 0; mi < 8; ++mi) {
                int gr0 = brow + wm * 128 + mi * 16 + fq * 4;   // b*2048+s
                int bbat = gr0 >> 11;
                int sl2 = gr0 & 2047;
                alignas(8) ushort_t tmp[4];
                #pragma unroll
                for (int j = 0; j < 4; ++j)
                    tmp[j] = f2bf(acc[mi][ni][j] + bb);
                *(v4s*)(Vt + (size_t)bbat * (1024 * 2048) + (size_t)cg * 2048 + sl2) =
                    *(const v4s*)tmp;
            }
        }
    }
}

// ---------------------------------------------------------------------------
// r10-proven single-barrier ring-3 GEMM.
// MODE 2: causal QK^T, 512 thr, 128x256, grid 288, fp16 scores out
// MODE 3: PV, 256 thr, 128x128, grid 512, kEnd=(by+1)*128, LPT order
template <int MODE>
__global__ __launch_bounds__(MODE == 3 ? 256 : 512)
void gemm_ring(const ushort_t* __restrict__ A, int lda, long long strideA,
               const ushort_t* __restrict__ Bt, int ldb, long long strideB,
               void* __restrict__ Cv, int ldc, long long strideC, int K)
{
    constexpr int THREADS = (MODE == 3) ? 256 : 512;
    constexpr int BN      = (MODE == 3) ? 128 : 256;
    constexpr int NW      = THREADS / 64;
    constexpr int RPL     = THREADS / 4;
    constexpr int ALINES  = 128 / RPL;
    constexpr int BLINES  = BN / RPL;
    constexpr int LOADS   = ALINES + BLINES;

    int bx, by, bz;
    int f = blockIdx.x;
    if constexpr (MODE == 2) {
        int swz = (f & 7) * 36 + (f >> 3);     // 288 = 8*36 bijective
        bz = swz / 72; int t = swz % 72;
        int r = 0, c = 0;
        while (c + (r / 2 + 1) <= t) { c += r / 2 + 1; ++r; }
        by = r; bx = t - c;                    // cols per row-block: by/2+1
    } else {
        int swz = (f & 7) * 64 + (f >> 3);     // 512 = 8*64 bijective
        bz = swz >> 7; int rem = swz & 127;
        by = 15 - (rem >> 3); bx = rem & 7;    // long (high-K) blocks first
    }

    const int tid = threadIdx.x;
    const int lane = tid & 63, wid = tid >> 6;
    const int wm = (NW == 8) ? (wid >> 2) : (wid >> 1);
    const int wc = wid & ((NW == 8) ? 3 : 1);

    const ushort_t* Ab = A + (size_t)bz * strideA;
    const ushort_t* Bb = Bt + (size_t)bz * strideB;

    __shared__ ushort_t As[3][128 * 32];
    __shared__ ushort_t Bs[3][BN * 32];

    const int brow = by * 128, bcol = bx * BN;

    int kEnd = K;
    if constexpr (MODE == 3) { int lim = (by + 1) * 128; kEnd = lim < K ? lim : K; }
    const int nt = kEnd / 32;

    v4f acc[4][4];
    #pragma unroll
    for (int mi = 0; mi < 4; ++mi)
        #pragma unroll
        for (int ni = 0; ni < 4; ++ni)
            acc[mi][ni] = (v4f)0.f;

    const int rr = tid >> 2, slot = tid & 3;
    auto STAGE = [&](int buf, int t) {
        const int k0 = t * 32;
        #pragma unroll
        for (int c = 0; c < ALINES; ++c) {
            int r = c * RPL + rr;
            int sc = ((slot ^ ((r >> 1) & 3)) << 3);
            load_lds16(Ab + (size_t)(brow + r) * lda + k0 + sc,
                       &As[buf][(size_t)(c * RPL + wid * 16) * 32]);
        }
        #pragma unroll
        for (int c = 0; c < BLINES; ++c) {
            int r = c * RPL + rr;
            int sc = ((slot ^ ((r >> 1) & 3)) << 3);
            load_lds16(Bb + (size_t)(bcol + r) * ldb + k0 + sc,
                       &Bs[buf][(size_t)(c * RPL + wid * 16) * 32]);
        }
    };

    const int frow = lane & 15, fq4 = lane >> 4;
    const int csw = ((fq4 ^ ((frow >> 1) & 3)) << 3);

    STAGE(0, 0);
    if (nt > 1) STAGE(1, 1);

    int cur = 0;
    for (int t = 0; t < nt; ++t) {
        if (t + 1 < nt) {
            asm volatile("s_waitcnt vmcnt(%0)" :: "i"(LOADS) : "memory");
        } else {
            asm volatile("s_waitcnt vmcnt(0)" ::: "memory");
        }
        BAR();
        if (t + 2 < nt) {
            int tgt = cur ? cur - 1 : 2;
            STAGE(tgt, t + 2);
        }
        const ushort_t* Ac = &As[cur][0];
        const ushort_t* Bc = &Bs[cur][0];
        v8s a[4], b[4];
        #pragma unroll
        for (int mi = 0; mi < 4; ++mi)
            a[mi] = *(const v8s*)(Ac + (size_t)(wm * 64 + mi * 16 + frow) * 32 + csw);
        #pragma unroll
        for (int ni = 0; ni < 4; ++ni)
            b[ni] = *(const v8s*)(Bc + (size_t)(wc * 64 + ni * 16 + frow) * 32 + csw);
        __builtin_amdgcn_s_setprio(1);
        #pragma unroll
        for (int mi = 0; mi < 4; ++mi)
            #pragma unroll
            for (int ni = 0; ni < 4; ++ni)
                acc[mi][ni] = __builtin_amdgcn_mfma_f32_16x16x32_bf16(a[mi], b[ni], acc[mi][ni], 0, 0, 0);
        __builtin_amdgcn_s_setprio(0);
        cur = (cur == 2) ? 0 : cur + 1;
    }

    const int fr = lane & 15;
    const int fq = lane >> 4;
    if constexpr (MODE == 2) {
        ushort_t* C = (ushort_t*)Cv + (size_t)bz * strideC;
        #pragma unroll
        for (int ni = 0; ni < 4; ++ni) {
            int gc = bcol + wc * 64 + ni * 16 + fr;
            #pragma unroll
            for (int mi = 0; mi < 4; ++mi) {
                int gr0 = brow + wm * 64 + mi * 16 + fq * 4;
                #pragma unroll
                for (int j = 0; j < 4; ++j)
                    C[(size_t)(gr0 + j) * ldc + gc] = f2h(acc[mi][ni][j]);
            }
        }
    } else {
        float* C = (float*)Cv + (size_t)bz * strideC;
        #pragma unroll
        for (int ni = 0; ni < 4; ++ni) {
            int gc = bcol + wc * 64 + ni * 16 + fr;
            #pragma unroll
            for (int mi = 0; mi < 4; ++mi) {
                int gr0 = brow + wm * 64 + mi * 16 + fq * 4;
                #pragma unroll
                for (int j = 0; j < 4; ++j)
                    C[(size_t)(gr0 + j) * ldc + gc] = acc[mi][ni][j];
            }
        }
    }
}

// ---------------------------------------------------------------------------
// causal row softmax, wave-per-row (no cross-wave sync): 2048 blocks x 4
// waves. fp16 scores -> bf16 P in place; zeros up to Lw = roundup128(i+1).
__global__ __launch_bounds__(256) void softmax_causal(ushort_t* __restrict__ Sc) {
    __shared__ float vals[4][2048];
    const int wid = threadIdx.x >> 6, lane = threadIdx.x & 63;
    const int row = blockIdx.x * 4 + wid;    // b*2048 + i
    const int b = row >> 11, i = row & 2047;
    ushort_t* srow = Sc + ((size_t)b * 2048 + i) * 2048;
    const int L = i + 1;
    const int Lw = ((i >> 7) + 1) << 7;
    float* v = vals[wid];

    float mx = -3.0e38f;
    const int L4 = L >> 2;
    for (int j4 = lane; j4 < L4; j4 += 64) {
        v4s u = *(const v4s*)(srow + j4 * 4);
        float4 w;
        w.x = h2f((unsigned short)u[0]); w.y = h2f((unsigned short)u[1]);
        w.z = h2f((unsigned short)u[2]); w.w = h2f((unsigned short)u[3]);
        ((float4*)v)[j4] = w;
        mx = fmaxf(fmaxf(mx, fmaxf(w.x, w.y)), fmaxf(w.z, w.w));
    }
    {
        int j = (L4 << 2) + lane;
        if (j < L) { float t = h2f(srow[j]); v[j] = t; mx = fmaxf(mx, t); }
    }
    #pragma unroll
    for (int o = 32; o; o >>= 1) mx = fmaxf(mx, __shfl_xor(mx, o));

    float sum = 0.f;
    for (int j = lane; j < L; j += 64) {
        float e = __expf(v[j] - mx);
        v[j] = e;
        sum += e;
    }
    #pragma unroll
    for (int o = 32; o; o >>= 1) sum += __shfl_xor(sum, o);
    float inv = 1.f / sum;

    for (int j4 = lane; j4 * 4 < Lw; j4 += 64) {
        int j = j4 * 4;
        float4 w = ((const float4*)v)[j4];
        v4s p;
        p[0] = (short)f2bf((j     < L) ? w.x * inv : 0.f);
        p[1] = (short)f2bf((j + 1 < L) ? w.y * inv : 0.f);
        p[2] = (short)f2bf((j + 2 < L) ? w.z * inv : 0.f);
        p[3] = (short)f2bf((j + 3 < L) ? w.w * inv : 0.f);
        *(v4s*)(srow + j) = p;
    }
}

// ---------------------------------------------------------------------------
extern "C" void kernel_launch(void* const* d_in, const int* in_sizes, int n_in,
                              void* d_out, int out_size, void* d_ws, size_t ws_size,
                              hipStream_t stream) {
    const float* x  = (const float*)d_in[0];
    // d_in[1] = additive causal mask: structurally known, not read.
    const float* Wq = (const float*)d_in[2];
    const float* bq = (const float*)d_in[3];
    const float* Wk = (const float*)d_in[4];
    const float* bk = (const float*)d_in[5];
    const float* Wv = (const float*)d_in[6];
    const float* bv = (const float*)d_in[7];

    ushort_t* xb = (ushort_t*)d_ws;                        // 16.78 MB
    ushort_t* Wt = xb + (size_t)8192 * 1024;               //  6.29 MB (3x1024x1024)
    ushort_t* Qb = Wt + (size_t)3 * 1024 * 1024;           // 16.78 MB (scaled 1/32)
    ushort_t* Kb = Qb + (size_t)8192 * 1024;               // 16.78 MB
    ushort_t* Vt = Kb + (size_t)8192 * 1024;               // 16.78 MB (4x[1024][2048])
    ushort_t* Sc = Vt + (size_t)8192 * 1024;               // 33.55 MB (fp16 S / bf16 P)

    // prep: x->bf16 + W transpose in one dispatch
    prep_kernel<<<5120, 256, 0, stream>>>((const float4*)x, xb, Wq, Wk, Wv, Wt);

    // fused QKV projection: 8-phase 256x192, 512 blocks = 2.0 exact rounds
    gemm8_qkv<<<512, 512, 0, stream>>>(xb, Wt, bq, bk, bv, Qb, Kb, Vt);

    // scores = Q K^T (causal, 128x256 tiles, 288 blocks, fp16 out)
    gemm_ring<2><<<288, 512, 0, stream>>>(Qb, 1024, 2048LL * 1024,
                                          Kb, 1024, 2048LL * 1024,
                                          Sc, 2048, 2048LL * 2048, 1024);

    softmax_causal<<<2048, 256, 0, stream>>>(Sc);

    // O = P V (128x128 tiles, 512 blocks, K limited per 128-row block)
    gemm_ring<3><<<512, 256, 0, stream>>>(Sc, 2048, 2048LL * 2048,
                                          Vt, 2048, 2048LL * 1024,
                                          d_out, 1024, 2048LL * 1024, 2048);
    (void)in_sizes; (void)n_in; (void)out_size; (void)ws_size;
}